// Round 9
// baseline (370.406 us; speedup 1.0000x reference)
//
#include <hip/hip_runtime.h>

// Problem constants
constexpr int kH  = 8;     // heads
constexpr int kD  = 16;    // dim per head
constexpr int kHD = 128;   // H*D
constexpr int kN  = 32;    // neighbors
constexpr int kE  = 32;    // edge feature dim
constexpr int kD0 = 128;   // feats0 channels
constexpr int kD1 = 64;    // feats1 channels

constexpr float SCALE0   = 0.25f;                 // 1/sqrt(16)
constexpr float SCALE1   = 0.14433756729740643f;  // 1/sqrt(48)
constexpr float SHARED_S = 0.70710678118654752f;  // sqrt(0.5)
constexpr float NEGV     = -1e9f;

// ---------------------------------------------------------------------------
// R8: ONE WAVE = ONE POSITION. 2048 blocks x 64 threads, LDS ~11.8 KB.
// R7 diagnosis: VALUBusy 14% -> 77% of block time is waiting, and the six
// __syncthreads lock all 4 waves into the same phase, so every HBM latency
// on the critical path stalls the whole block. Here each position's full
// pipeline (selfKV GEMV, scores, softmax, attn*V, out-proj) lives in a single
// wave: barriers are intra-wave no-ops, phases of different positions overlap
// freely across the 8 resident waves/CU, and launch_bounds(64,1) gives the
// allocator ~256 VGPRs so it can hoist B1 k-loads / D v-loads across earlier
// compute (the R5 prefetch that spilled at a 64-reg budget now has headroom).
// Edge-bias is computed inline in B1 from global edges (same rows re-read by
// the 8 head-quads hit L1), eliminating the edg/biasL LDS arrays.
// ---------------------------------------------------------------------------
__global__ __launch_bounds__(64, 1) void se3_wave(
    const float* __restrict__ q0, const float* __restrict__ q1,
    const float* __restrict__ k0, const float* __restrict__ k1,
    const float* __restrict__ v0, const float* __restrict__ v1,
    const float* __restrict__ feats0, const float* __restrict__ feats1,
    const float* __restrict__ edges,
    const float* __restrict__ Wskv0, const float* __restrict__ Wskv1,
    const float* __restrict__ Wbias,
    const float* __restrict__ sbias, const float* __restrict__ nbias,
    const float* __restrict__ nk0, const float* __restrict__ nk1,
    const float* __restrict__ nv0, const float* __restrict__ nv1,
    const float* __restrict__ hw1,
    const float* __restrict__ Wout0, const float* __restrict__ Wout1,
    const int* __restrict__ nmask,
    float* __restrict__ out, int n_total)
{
  const int i  = blockIdx.x;
  const int t  = threadIdx.x;   // 0..63, one wave
  const int q4 = t & 3;         // quad lane
  const int qq = t >> 2;        // quad 0..15

  __shared__ __align__(16) float f0s[kD0];        // 128
  __shared__ __align__(16) float f1s[kD1 * 3];    // 192
  __shared__ __align__(16) float q0s[kHD];        // 128
  __shared__ __align__(16) float q1s[kHD * 3];    // 384
  __shared__ __align__(16) float wbs[kH * kE];    // 256 [h][e]
  __shared__ float w1s[kH];
  __shared__ int   nmL[kN];
  __shared__ float sk0[kHD];                      // 128
  __shared__ __align__(16) float sk1[kHD * 3];    // 384
  __shared__ __align__(16) float sv0[kHD];        // 128
  __shared__ __align__(16) float sv1[kHD * 3];    // 384
  __shared__ float sc[kH][36];                    // 288 (34 used)
  __shared__ __align__(16) float o0L[kHD];        // 128
  __shared__ __align__(16) float o1L[kHD * 3];    // 384

  // ---------------- stage (one wave; every segment contiguous) ----------------
  if (t < 32) ((float4*)f0s)[t] = ((const float4*)(feats0 + (size_t)i * kD0))[t];
  if (t < 48) ((float4*)f1s)[t] = ((const float4*)(feats1 + (size_t)i * kD1 * 3))[t];
  if (t < 32) ((float4*)q0s)[t] = ((const float4*)(q0 + (size_t)i * kHD))[t];
  #pragma unroll
  for (int u = t; u < 96; u += 64)
    ((float4*)q1s)[u] = ((const float4*)(q1 + (size_t)i * kHD * 3))[u];
  ((float4*)wbs)[t] = ((const float4*)Wbias)[t];      // 64 f4 = 256 floats
  if (t < kN) nmL[t] = nmask[(size_t)i * kN + t];
  if (t < kH) w1s[t] = log1pf(expf(hw1[t]));
  __syncthreads();

  // ---------------- Phase A: selfKV, 256 W-rows over 16 quads x 16 passes -----
  #pragma unroll 4
  for (int pass = 0; pass < 16; ++pass) {
    const int r = qq + 16 * pass;          // W row 0..255
    const float4* w0r = (const float4*)(Wskv0 + (size_t)r * kD0);
    float a0 = 0.f;
    #pragma unroll
    for (int g = 0; g < 8; ++g) {
      float4 w = w0r[q4 + 4 * g]; int c = (q4 + 4 * g) * 4;
      a0 += w.x * f0s[c] + w.y * f0s[c + 1]
          + w.z * f0s[c + 2] + w.w * f0s[c + 3];
    }
    const float4* w1r = (const float4*)(Wskv1 + (size_t)r * kD1);
    float a1[3] = {};
    #pragma unroll
    for (int g = 0; g < 4; ++g) {
      float4 w = w1r[q4 + 4 * g]; int c = (q4 + 4 * g) * 4;
      float wvv[4] = {w.x, w.y, w.z, w.w};
      #pragma unroll
      for (int k = 0; k < 4; ++k) {
        const float* fp = &f1s[(c + k) * 3];
        a1[0] += wvv[k] * fp[0];
        a1[1] += wvv[k] * fp[1];
        a1[2] += wvv[k] * fp[2];
      }
    }
    a0 += __shfl_xor(a0, 1); a0 += __shfl_xor(a0, 2);
    #pragma unroll
    for (int c = 0; c < 3; ++c) {
      a1[c] += __shfl_xor(a1[c], 1);
      a1[c] += __shfl_xor(a1[c], 2);
    }
    if (q4 == 0) {
      if (r < kHD) {
        sk0[r] = a0;
        sk1[r * 3 + 0] = a1[0]; sk1[r * 3 + 1] = a1[1]; sk1[r * 3 + 2] = a1[2];
      } else {
        const int o = r - kHD;
        sv0[o] = a0;
        sv1[o * 3 + 0] = a1[0]; sv1[o * 3 + 1] = a1[1]; sv1[o * 3 + 2] = a1[2];
      }
    }
  }
  __syncthreads();

  // ---------------- Phase B0: null/self scores (t<16) ----------------
  if (t < 16) {
    const int h = t & 7;
    const bool is_self = t >= 8;
    float s0 = 0.f, s1 = 0.f, bias;
    if (is_self) {
      #pragma unroll
      for (int d = 0; d < kD; ++d) s0 += q0s[h * kD + d] * sk0[h * kD + d];
      #pragma unroll
      for (int x = 0; x < 48; ++x) s1 += q1s[h * 48 + x] * sk1[h * 48 + x];
      bias = sbias[h];
    } else {
      #pragma unroll
      for (int d = 0; d < kD; ++d) s0 += q0s[h * kD + d] * nk0[h * kD + d];
      #pragma unroll
      for (int x = 0; x < 48; ++x) s1 += q1s[h * 48 + x] * nk1[h * 48 + x];
      bias = nbias[h];
    }
    sc[h][is_self ? 1 : 0] =
        (s0 * SCALE0 + bias + s1 * SCALE1 * w1s[h]) * SHARED_S;
  }

  // ---------------- Phase B1: neighbor scores (quad = (h, j-half)) ----------
  {
    const int h  = qq & 7;
    const int jh = qq >> 3;      // 0..1 -> j = jh*16 + jj
    const float w1h = w1s[h];
    float wbf[8];
    #pragma unroll
    for (int e = 0; e < 8; ++e) wbf[e] = wbs[h * kE + q4 * 8 + e];
    const float4 q0f = *((const float4*)(q0s + h * kD) + q4);
    float4 q1f[3];
    #pragma unroll
    for (int pc = 0; pc < 3; ++pc)
      q1f[pc] = *((const float4*)(q1s + h * 48 + pc * 16) + q4);

    const float* k0base = k0 + (size_t)i * kN * kHD + h * kD + q4 * 4;
    const float* k1base = k1 + (size_t)i * kN * kHD * 3 + h * 48 + q4 * 4;
    const float* ebase  = edges + (size_t)i * kN * kE + q4 * 8;

    #pragma unroll 4
    for (int jj = 0; jj < 16; ++jj) {
      const int j = jh * 16 + jj;
      float4 ka = *((const float4*)(k0base + (size_t)j * kHD));
      float4 kb0 = *((const float4*)(k1base + (size_t)j * kHD * 3));
      float4 kb1 = *((const float4*)(k1base + (size_t)j * kHD * 3 + 16));
      float4 kb2 = *((const float4*)(k1base + (size_t)j * kHD * 3 + 32));
      float4 e0 = ((const float4*)(ebase + (size_t)j * kE))[0];
      float4 e1 = ((const float4*)(ebase + (size_t)j * kE))[1];

      float s0 = ka.x * q0f.x + ka.y * q0f.y + ka.z * q0f.z + ka.w * q0f.w;
      float s1 = kb0.x * q1f[0].x + kb0.y * q1f[0].y
               + kb0.z * q1f[0].z + kb0.w * q1f[0].w
               + kb1.x * q1f[1].x + kb1.y * q1f[1].y
               + kb1.z * q1f[1].z + kb1.w * q1f[1].w
               + kb2.x * q1f[2].x + kb2.y * q1f[2].y
               + kb2.z * q1f[2].z + kb2.w * q1f[2].w;
      float bias = e0.x * wbf[0] + e0.y * wbf[1] + e0.z * wbf[2] + e0.w * wbf[3]
                 + e1.x * wbf[4] + e1.y * wbf[5] + e1.z * wbf[6] + e1.w * wbf[7];

      float part = s0 * SCALE0 + s1 * SCALE1 * w1h + bias;
      part += __shfl_xor(part, 1);
      part += __shfl_xor(part, 2);
      if (q4 == 0) sc[h][2 + j] = nmL[j] ? part * SHARED_S : NEGV;
    }
  }
  __syncthreads();

  // ---------------- Phase C: softmax (8 heads x 8 lanes) ----------------
  {
    const int h = t >> 3, l = t & 7;
    float* rp = sc[h];
    float va = rp[2 + l], vb = rp[2 + l + 8], vc = rp[2 + l + 16], vd = rp[2 + l + 24];
    float mx = fmaxf(fmaxf(va, vb), fmaxf(vc, vd));
    #pragma unroll
    for (int off = 4; off > 0; off >>= 1) mx = fmaxf(mx, __shfl_xor(mx, off));
    float e0v = rp[0], e1v = rp[1];
    mx = fmaxf(mx, fmaxf(e0v, e1v));
    float ea = __expf(va - mx), eb = __expf(vb - mx);
    float ec = __expf(vc - mx), ed = __expf(vd - mx);
    float sum = (ea + eb) + (ec + ed);
    #pragma unroll
    for (int off = 4; off > 0; off >>= 1) sum += __shfl_xor(sum, off);
    float ee0 = __expf(e0v - mx), ee1 = __expf(e1v - mx);
    float inv = 1.f / (sum + ee0 + ee1);
    rp[2 + l] = ea * inv;
    rp[2 + l + 8] = eb * inv;
    rp[2 + l + 16] = ec * inv;
    rp[2 + l + 24] = ed * inv;
    if (l == 0) rp[0] = ee0 * inv;
    if (l == 1) rp[1] = ee1 * inv;
  }
  __syncthreads();

  // ---------------- Phase D: attn*V — 128 f4-chunks, 2 per lane ----------
  {
    // chunk 1: c = t (lanes 0-31: o0 chunk t; lanes 32-63: o1 chunk t-32)
    if (t < 32) {
      const int s = t, h = s >> 2;
      const float* at = sc[h];
      float4 nv = ((const float4*)nv0)[s];
      float4 sv = ((const float4*)sv0)[s];
      float4 acc;
      acc.x = at[0] * nv.x + at[1] * sv.x;
      acc.y = at[0] * nv.y + at[1] * sv.y;
      acc.z = at[0] * nv.z + at[1] * sv.z;
      acc.w = at[0] * nv.w + at[1] * sv.w;
      const float4* vp = (const float4*)(v0 + (size_t)i * kN * kHD) + s;
      float4 vbuf[8];
      #pragma unroll
      for (int g = 0; g < 4; ++g) {
        #pragma unroll
        for (int r = 0; r < 8; ++r) vbuf[r] = vp[(g * 8 + r) * 32];
        #pragma unroll
        for (int r = 0; r < 8; ++r) {
          float a = at[2 + g * 8 + r];
          acc.x += a * vbuf[r].x; acc.y += a * vbuf[r].y;
          acc.z += a * vbuf[r].z; acc.w += a * vbuf[r].w;
        }
      }
      ((float4*)o0L)[s] = acc;
    } else {
      const int s1 = t - 32, h = s1 / 12;
      const float* at = sc[h];
      float4 nv = ((const float4*)nv1)[s1];
      float4 sv = ((const float4*)sv1)[s1];
      float4 acc;
      acc.x = at[0] * nv.x + at[1] * sv.x;
      acc.y = at[0] * nv.y + at[1] * sv.y;
      acc.z = at[0] * nv.z + at[1] * sv.z;
      acc.w = at[0] * nv.w + at[1] * sv.w;
      const float4* vp = (const float4*)(v1 + (size_t)i * kN * kHD * 3) + s1;
      float4 vbuf[8];
      #pragma unroll
      for (int g = 0; g < 4; ++g) {
        #pragma unroll
        for (int r = 0; r < 8; ++r) vbuf[r] = vp[(g * 8 + r) * 96];
        #pragma unroll
        for (int r = 0; r < 8; ++r) {
          float a = at[2 + g * 8 + r];
          acc.x += a * vbuf[r].x; acc.y += a * vbuf[r].y;
          acc.z += a * vbuf[r].z; acc.w += a * vbuf[r].w;
        }
      }
      ((float4*)o1L)[s1] = acc;
    }
    // chunk 2: o1 chunk s1 = t + 32 (wave-uniform)
    {
      const int s1 = t + 32, h = s1 / 12;
      const float* at = sc[h];
      float4 nv = ((const float4*)nv1)[s1];
      float4 sv = ((const float4*)sv1)[s1];
      float4 acc;
      acc.x = at[0] * nv.x + at[1] * sv.x;
      acc.y = at[0] * nv.y + at[1] * sv.y;
      acc.z = at[0] * nv.z + at[1] * sv.z;
      acc.w = at[0] * nv.w + at[1] * sv.w;
      const float4* vp = (const float4*)(v1 + (size_t)i * kN * kHD * 3) + s1;
      float4 vbuf[8];
      #pragma unroll
      for (int g = 0; g < 4; ++g) {
        #pragma unroll
        for (int r = 0; r < 8; ++r) vbuf[r] = vp[(g * 8 + r) * 96];
        #pragma unroll
        for (int r = 0; r < 8; ++r) {
          float a = at[2 + g * 8 + r];
          acc.x += a * vbuf[r].x; acc.y += a * vbuf[r].y;
          acc.z += a * vbuf[r].z; acc.w += a * vbuf[r].w;
        }
      }
      ((float4*)o1L)[s1] = acc;
    }
  }
  __syncthreads();

  // ---------------- Phase E: out-proj, 320 rows over 16 quads x 20 passes ----
  #pragma unroll 2
  for (int p = 0; p < 20; ++p) {
    const int u = 16 * p + qq;          // pass-uniform branch (16p+15 < 128 iff p<8)
    if (u < 128) {
      const float4* wr = (const float4*)(Wout0 + (size_t)u * kHD);
      float a = 0.f;
      #pragma unroll
      for (int g = 0; g < 8; ++g) {
        float4 w = wr[q4 + 4 * g]; int c = (q4 + 4 * g) * 4;
        a += w.x * o0L[c] + w.y * o0L[c + 1]
           + w.z * o0L[c + 2] + w.w * o0L[c + 3];
      }
      a += __shfl_xor(a, 1); a += __shfl_xor(a, 2);
      if (q4 == 0) out[(size_t)i * kHD + u] = a;
    } else {
      const int v2 = u - 128, o = v2 / 3, m = v2 - o * 3;
      const float4* wr = (const float4*)(Wout1 + (size_t)o * kHD);
      float a = 0.f;
      #pragma unroll
      for (int g = 0; g < 8; ++g) {
        float4 w = wr[q4 + 4 * g]; int c = (q4 + 4 * g) * 4;
        a += w.x * o1L[(c + 0) * 3 + m] + w.y * o1L[(c + 1) * 3 + m]
           + w.z * o1L[(c + 2) * 3 + m] + w.w * o1L[(c + 3) * 3 + m];
      }
      a += __shfl_xor(a, 1); a += __shfl_xor(a, 2);
      if (q4 == 0)
        out[(size_t)n_total * kHD + (size_t)i * 192 + v2] = a;
    }
  }
}

extern "C" void kernel_launch(void* const* d_in, const int* in_sizes, int n_in,
                              void* d_out, int out_size, void* d_ws, size_t ws_size,
                              hipStream_t stream) {
  const int n = in_sizes[0] / kHD;  // 2048
  const float* q0     = (const float*)d_in[0];
  const float* k0     = (const float*)d_in[1];
  const float* v0     = (const float*)d_in[2];
  const float* q1     = (const float*)d_in[3];
  const float* k1     = (const float*)d_in[4];
  const float* v1     = (const float*)d_in[5];
  const float* feats0 = (const float*)d_in[6];
  const float* feats1 = (const float*)d_in[7];
  const float* edges  = (const float*)d_in[8];
  const float* Wskv0  = (const float*)d_in[9];
  const float* Wskv1  = (const float*)d_in[10];
  const float* Wbias  = (const float*)d_in[11];
  const float* sbias  = (const float*)d_in[12];
  const float* nbias  = (const float*)d_in[13];
  const float* nk0    = (const float*)d_in[14];
  const float* nv0    = (const float*)d_in[15];
  const float* nk1    = (const float*)d_in[16];
  const float* nv1    = (const float*)d_in[17];
  const float* hw1    = (const float*)d_in[18];
  const float* Wout0  = (const float*)d_in[19];
  const float* Wout1  = (const float*)d_in[20];
  const int*   nmask  = (const int*)d_in[21];

  se3_wave<<<n, 64, 0, stream>>>(
      q0, q1, k0, k1, v0, v1, feats0, feats1, edges,
      Wskv0, Wskv1, Wbias, sbias, nbias, nk0, nk1, nv0, nv1, hw1,
      Wout0, Wout1, nmask, (float*)d_out, n);
}

// Round 10
// 331.335 us; speedup vs baseline: 1.1179x; 1.1179x over previous
//
#include <hip/hip_runtime.h>

// Problem constants
constexpr int kH  = 8;     // heads
constexpr int kD  = 16;    // dim per head
constexpr int kHD = 128;   // H*D
constexpr int kN  = 32;    // neighbors
constexpr int kE  = 32;    // edge feature dim
constexpr int kD0 = 128;   // feats0 channels
constexpr int kD1 = 64;    // feats1 channels

constexpr float SCALE0   = 0.25f;                 // 1/sqrt(16)
constexpr float SCALE1   = 0.14433756729740643f;  // 1/sqrt(48)
constexpr float SHARED_S = 0.70710678118654752f;  // sqrt(0.5)
constexpr float NEGV     = -1e9f;

// ---------------------------------------------------------------------------
// R9: fused kernel restructured as a CONTINUOUS STREAM. R7 (117us) moved its
// 128 KB/position of k/v in two short bursts separated by compute+barriers ->
// in-flight bytes/CU far below Little's-law need -> 2.4 TB/s delivered.
// Here k and v stream through two 16 KB LDS buffers in 8-row chunks via
// global_load_lds (async, ZERO VGPR cost -- the R5/R6 register prefetch
// spilled). Chunks 0+1 fly under Phase A's W-GEMV; each loop iter issues
// chunk c+1 then computes chunk c; the barrier's implicit vmcnt drain retires
// it one compute-phase later. LDS ~42 KB -> 3 blocks/CU (m114: enough for
// implicit cross-block overlap). o-partials alias dead q/sk scratch.
// ---------------------------------------------------------------------------

__device__ __forceinline__ void gll16(const void* g, void* l) {
  __builtin_amdgcn_global_load_lds(
      (const __attribute__((address_space(1))) void*)(g),
      (__attribute__((address_space(3))) void*)(l), 16, 0, 0);
}

// stage one 8-row chunk: p0 rows (8*128f = 4KB) + p1 rows (8*384f = 12KB)
// into buf[0..1023] and buf[1024..4095] (floats). Contiguous global source.
__device__ __forceinline__ void stage_chunk(
    const float* p0, const float* p1, int i, int c, float* buf, int t) {
  const char* g0 = (const char*)(p0 + (size_t)i * kN * kHD + (size_t)c * 8 * kHD) + t * 16;
  const char* g1 = (const char*)(p1 + (size_t)i * kN * kHD * 3 + (size_t)c * 8 * kHD * 3) + t * 16;
  char* l = (char*)buf + ((t >> 6) << 10);     // wave-uniform base
  gll16(g0, l);
  #pragma unroll
  for (int o = 0; o < 3; ++o)
    gll16(g1 + o * 4096, l + 4096 + o * 4096);
}

__global__ __launch_bounds__(256, 4) void se3_stream(
    const float* __restrict__ q0, const float* __restrict__ q1,
    const float* __restrict__ k0, const float* __restrict__ k1,
    const float* __restrict__ v0, const float* __restrict__ v1,
    const float* __restrict__ feats0, const float* __restrict__ feats1,
    const float* __restrict__ edges,
    const float* __restrict__ Wskv0, const float* __restrict__ Wskv1,
    const float* __restrict__ Wbias,
    const float* __restrict__ sbias, const float* __restrict__ nbias,
    const float* __restrict__ nk0, const float* __restrict__ nk1,
    const float* __restrict__ nv0, const float* __restrict__ nv1,
    const float* __restrict__ hw1,
    const float* __restrict__ Wout0, const float* __restrict__ Wout1,
    const int* __restrict__ nmask,
    float* __restrict__ out, int n_total)
{
  const int i  = blockIdx.x;
  const int t  = threadIdx.x;
  const int q4 = t & 3;        // quad lane
  const int qg = t >> 2;       // quad group 0..63
  const int hB = qg & 7;       // B1/score head
  const int jj = t >> 5;       // B1 chunk-row 0..7

  __shared__ __align__(16) float kv[2][4096];     // 2 x 16 KB stream buffers
  __shared__ __align__(16) float scratch[1024];   // q+sk, later o-partials
  __shared__ __align__(16) float f0s[kD0];
  __shared__ __align__(16) float f1s[kD1 * 3];
  __shared__ __align__(16) float sv0[kHD];
  __shared__ __align__(16) float sv1[kHD * 3];
  __shared__ float sc[kH][36];
  __shared__ float biasL[kH][kN];
  __shared__ float w1s[kH];
  __shared__ int   nmL[kN];

  float* q0s = scratch;            // 128 f
  float* q1s = scratch + 128;      // 384 f
  float* sk0 = scratch + 512;      // 128 f
  float* sk1 = scratch + 640;      // 384 f
  // after D: o0p[h] = scratch + h*128 (256 f), o1p[h] = scratch + 256 + h*384

  // ---------------- stage small inputs ----------------
  if (t < 32) {
    ((float4*)f0s)[t] = ((const float4*)(feats0 + (size_t)i * kD0))[t];
  } else if (t < 80) {
    ((float4*)f1s)[t - 32] = ((const float4*)(feats1 + (size_t)i * kD1 * 3))[t - 32];
  } else if (t < 112) {
    ((float4*)q0s)[t - 80] = ((const float4*)(q0 + (size_t)i * kHD))[t - 80];
  } else if (t < 208) {
    ((float4*)q1s)[t - 112] = ((const float4*)(q1 + (size_t)i * kHD * 3))[t - 112];
  }
  if (t < kN) nmL[t] = nmask[(size_t)i * kN + t];
  if (t < kH) w1s[t] = log1pf(expf(hw1[t]));
  __syncthreads();

  // k chunks 0 and 1 fly under Phase A (32 KB in flight, no VGPR held)
  stage_chunk(k0, k1, i, 0, kv[0], t);
  stage_chunk(k0, k1, i, 1, kv[1], t);

  // ---------------- Phase A: selfKV (quad-cooperative W rows) ----------------
  #pragma unroll
  for (int pass = 0; pass < 4; ++pass) {
    const int r = qg + 64 * pass;          // W row 0..255
    const float4* w0r = (const float4*)(Wskv0 + (size_t)r * kD0);
    float a0 = 0.f;
    #pragma unroll
    for (int g = 0; g < 8; ++g) {
      float4 w = w0r[q4 + 4 * g]; int c = (q4 + 4 * g) * 4;
      a0 += w.x * f0s[c] + w.y * f0s[c + 1]
          + w.z * f0s[c + 2] + w.w * f0s[c + 3];
    }
    const float4* w1r = (const float4*)(Wskv1 + (size_t)r * kD1);
    float a1[3] = {};
    #pragma unroll
    for (int g = 0; g < 4; ++g) {
      float4 w = w1r[q4 + 4 * g]; int c = (q4 + 4 * g) * 4;
      float wvv[4] = {w.x, w.y, w.z, w.w};
      #pragma unroll
      for (int k = 0; k < 4; ++k) {
        const float* fp = &f1s[(c + k) * 3];
        a1[0] += wvv[k] * fp[0];
        a1[1] += wvv[k] * fp[1];
        a1[2] += wvv[k] * fp[2];
      }
    }
    a0 += __shfl_xor(a0, 1); a0 += __shfl_xor(a0, 2);
    #pragma unroll
    for (int c = 0; c < 3; ++c) {
      a1[c] += __shfl_xor(a1[c], 1);
      a1[c] += __shfl_xor(a1[c], 2);
    }
    if (q4 == 0) {
      if (r < kHD) {
        sk0[r] = a0;
        sk1[r * 3 + 0] = a1[0]; sk1[r * 3 + 1] = a1[1]; sk1[r * 3 + 2] = a1[2];
      } else {
        const int o = r - kHD;
        sv0[o] = a0;
        sv1[o * 3 + 0] = a1[0]; sv1[o * 3 + 1] = a1[1]; sv1[o * 3 + 2] = a1[2];
      }
    }
  }
  __syncthreads();   // also retires k chunks 0+1 (flew under A)

  // ---------------- pair-bias precompute + null/self scores ----------------
  {
    const int h = t >> 5, j = t & 31;
    const float4* er = (const float4*)(edges + (size_t)i * kN * kE + j * kE);
    const float4* wr = (const float4*)(Wbias + h * kE);
    float b = 0.f;
    #pragma unroll
    for (int g = 0; g < 8; ++g) {
      float4 e = er[g]; float4 w = wr[g];
      b += e.x * w.x + e.y * w.y + e.z * w.z + e.w * w.w;
    }
    biasL[h][j] = b;
  }
  if (t < 16) {
    const int h = t & 7;
    const bool is_self = t >= 8;
    float s0 = 0.f, s1 = 0.f, bias;
    if (is_self) {
      #pragma unroll
      for (int d = 0; d < kD; ++d) s0 += q0s[h * kD + d] * sk0[h * kD + d];
      #pragma unroll
      for (int x = 0; x < 48; ++x) s1 += q1s[h * 48 + x] * sk1[h * 48 + x];
      bias = sbias[h];
    } else {
      #pragma unroll
      for (int d = 0; d < kD; ++d) s0 += q0s[h * kD + d] * nk0[h * kD + d];
      #pragma unroll
      for (int x = 0; x < 48; ++x) s1 += q1s[h * 48 + x] * nk1[h * 48 + x];
      bias = nbias[h];
    }
    sc[h][is_self ? 1 : 0] =
        (s0 * SCALE0 + bias + s1 * SCALE1 * w1s[h]) * SHARED_S;
  }
  __syncthreads();

  // ---------------- Phase B: neighbor scores, 4 chunks of 8 j ----------------
  {
    const float w1h = w1s[hB];
    const float4 q0f = *((const float4*)(q0s + hB * kD) + q4);
    float4 q1f[3];
    #pragma unroll
    for (int pc = 0; pc < 3; ++pc)
      q1f[pc] = *((const float4*)(q1s + hB * 48 + pc * 16) + q4);

    #pragma unroll
    for (int c = 0; c < 4; ++c) {
      if (c >= 1) {
        if (c < 3) stage_chunk(k0, k1, i, c + 1, kv[(c + 1) & 1], t);
        else       stage_chunk(v0, v1, i, 0,     kv[0],           t);  // v stream starts
      }
      const float* kb = kv[c & 1];
      float4 ka = ((const float4*)(kb + jj * 128 + hB * 16))[q4];
      const float4* k1r = (const float4*)(kb + 1024 + jj * 384 + hB * 48);
      float4 kb0 = k1r[q4];
      float4 kb1 = k1r[q4 + 4];
      float4 kb2 = k1r[q4 + 8];

      float s0 = ka.x * q0f.x + ka.y * q0f.y + ka.z * q0f.z + ka.w * q0f.w;
      float s1 = kb0.x * q1f[0].x + kb0.y * q1f[0].y
               + kb0.z * q1f[0].z + kb0.w * q1f[0].w
               + kb1.x * q1f[1].x + kb1.y * q1f[1].y
               + kb1.z * q1f[1].z + kb1.w * q1f[1].w
               + kb2.x * q1f[2].x + kb2.y * q1f[2].y
               + kb2.z * q1f[2].z + kb2.w * q1f[2].w;

      float part = s0 * SCALE0 + s1 * SCALE1 * w1h;
      part += __shfl_xor(part, 1);
      part += __shfl_xor(part, 2);
      const int j = c * 8 + jj;
      if (q4 == 0)
        sc[hB][2 + j] = nmL[j] ? (part + biasL[hB][j]) * SHARED_S : NEGV;
      __syncthreads();   // retires chunk c+1 loads; frees kv[c&1]
    }
  }

  // ---------------- Phase C: softmax (8 heads x 16 lanes) ----------------
  if (t < 128) {
    const int h = t >> 4, l = t & 15;
    float* rp = sc[h];
    float va = rp[2 + l], vb = rp[2 + l + 16];
    float mx = fmaxf(va, vb);
    #pragma unroll
    for (int off = 8; off > 0; off >>= 1) mx = fmaxf(mx, __shfl_xor(mx, off));
    float e0v = rp[0], e1v = rp[1];
    mx = fmaxf(mx, fmaxf(e0v, e1v));
    float ea = __expf(va - mx), eb = __expf(vb - mx);
    float sum = ea + eb;
    #pragma unroll
    for (int off = 8; off > 0; off >>= 1) sum += __shfl_xor(sum, off);
    float ee0 = __expf(e0v - mx), ee1 = __expf(e1v - mx);
    float inv = 1.f / (sum + ee0 + ee1);
    rp[2 + l] = ea * inv;
    rp[2 + l + 16] = eb * inv;
    if (l == 0) rp[0] = ee0 * inv;
    if (l == 1) rp[1] = ee1 * inv;
  }
  __syncthreads();   // sc final; v-chunk0 (issued in B c=3) already retired

  // ---------------- Phase D: attn*V, streaming 4 chunks; acc in regs --------
  {
    const int half = t >> 7;       // splits each chunk's 8 rows: half*4 + 0..3
    const int s = t & 127;         // s<32: o0 f4-chunk s; else o1 f4-chunk s-32
    const int h = (s < 32) ? (s >> 2) : ((s - 32) / 12);
    const float* at = sc[h];

    float4 acc = {0.f, 0.f, 0.f, 0.f};
    if (half == 0) {
      if (s < 32) {
        float4 nv = ((const float4*)nv0)[s];
        float4 sv = ((const float4*)sv0)[s];
        acc.x = at[0] * nv.x + at[1] * sv.x;
        acc.y = at[0] * nv.y + at[1] * sv.y;
        acc.z = at[0] * nv.z + at[1] * sv.z;
        acc.w = at[0] * nv.w + at[1] * sv.w;
      } else {
        const int s1 = s - 32;
        float4 nv = ((const float4*)nv1)[s1];
        float4 sv = ((const float4*)sv1)[s1];
        acc.x = at[0] * nv.x + at[1] * sv.x;
        acc.y = at[0] * nv.y + at[1] * sv.y;
        acc.z = at[0] * nv.z + at[1] * sv.z;
        acc.w = at[0] * nv.w + at[1] * sv.w;
      }
    }

    #pragma unroll
    for (int c = 0; c < 4; ++c) {
      if (c < 3) stage_chunk(v0, v1, i, c + 1, kv[(c + 1) & 1], t);
      const float* vb = kv[c & 1];
      #pragma unroll
      for (int u = 0; u < 4; ++u) {
        const int jr = half * 4 + u;              // row within chunk
        const float a = at[2 + c * 8 + jr];
        float4 vv = (s < 32)
            ? ((const float4*)(vb + jr * 128))[s]
            : ((const float4*)(vb + 1024 + jr * 384))[s - 32];
        acc.x += a * vv.x; acc.y += a * vv.y;
        acc.z += a * vv.z; acc.w += a * vv.w;
      }
      __syncthreads();
    }

    // write partials into scratch (q/sk regions now dead)
    if (s < 32) ((float4*)(scratch + half * 128))[s] = acc;
    else        ((float4*)(scratch + 256 + half * 384))[s - 32] = acc;
  }
  __syncthreads();

  // combine halves: o0 -> scratch[0..127], o1 -> scratch[256..639]
  if (t < 128) {
    if (t < 32) {
      float4 a = ((float4*)scratch)[t], b = ((float4*)(scratch + 128))[t];
      a.x += b.x; a.y += b.y; a.z += b.z; a.w += b.w;
      ((float4*)scratch)[t] = a;
    } else {
      const int s1 = t - 32;
      float4 a = ((float4*)(scratch + 256))[s1], b = ((float4*)(scratch + 640))[s1];
      a.x += b.x; a.y += b.y; a.z += b.z; a.w += b.w;
      ((float4*)(scratch + 256))[s1] = a;
    }
  }
  __syncthreads();

  // ---------------- Phase E: output projections (quad-cooperative) ----------
  const float* o0L = scratch;
  const float* o1L = scratch + 256;
  #pragma unroll
  for (int pass = 0; pass < 5; ++pass) {
    const int u = qg + 64 * pass;          // 0..319 (pass-uniform branch)
    if (u < 128) {
      const float4* wr = (const float4*)(Wout0 + (size_t)u * kHD);
      float a = 0.f;
      #pragma unroll
      for (int g = 0; g < 8; ++g) {
        float4 w = wr[q4 + 4 * g]; int c = (q4 + 4 * g) * 4;
        a += w.x * o0L[c] + w.y * o0L[c + 1]
           + w.z * o0L[c + 2] + w.w * o0L[c + 3];
      }
      a += __shfl_xor(a, 1); a += __shfl_xor(a, 2);
      if (q4 == 0) out[(size_t)i * kHD + u] = a;
    } else {
      const int v2 = u - 128, o = v2 / 3, m = v2 - o * 3;
      const float4* wr = (const float4*)(Wout1 + (size_t)o * kHD);
      float a = 0.f;
      #pragma unroll
      for (int g = 0; g < 8; ++g) {
        float4 w = wr[q4 + 4 * g]; int c = (q4 + 4 * g) * 4;
        a += w.x * o1L[(c + 0) * 3 + m] + w.y * o1L[(c + 1) * 3 + m]
           + w.z * o1L[(c + 2) * 3 + m] + w.w * o1L[(c + 3) * 3 + m];
      }
      a += __shfl_xor(a, 1); a += __shfl_xor(a, 2);
      if (q4 == 0)
        out[(size_t)n_total * kHD + (size_t)i * 192 + v2] = a;
    }
  }
}

extern "C" void kernel_launch(void* const* d_in, const int* in_sizes, int n_in,
                              void* d_out, int out_size, void* d_ws, size_t ws_size,
                              hipStream_t stream) {
  const int n = in_sizes[0] / kHD;  // 2048
  const float* q0     = (const float*)d_in[0];
  const float* k0     = (const float*)d_in[1];
  const float* v0     = (const float*)d_in[2];
  const float* q1     = (const float*)d_in[3];
  const float* k1     = (const float*)d_in[4];
  const float* v1     = (const float*)d_in[5];
  const float* feats0 = (const float*)d_in[6];
  const float* feats1 = (const float*)d_in[7];
  const float* edges  = (const float*)d_in[8];
  const float* Wskv0  = (const float*)d_in[9];
  const float* Wskv1  = (const float*)d_in[10];
  const float* Wbias  = (const float*)d_in[11];
  const float* sbias  = (const float*)d_in[12];
  const float* nbias  = (const float*)d_in[13];
  const float* nk0    = (const float*)d_in[14];
  const float* nv0    = (const float*)d_in[15];
  const float* nk1    = (const float*)d_in[16];
  const float* nv1    = (const float*)d_in[17];
  const float* hw1    = (const float*)d_in[18];
  const float* Wout0  = (const float*)d_in[19];
  const float* Wout1  = (const float*)d_in[20];
  const int*   nmask  = (const int*)d_in[21];

  se3_stream<<<n, 256, 0, stream>>>(
      q0, q1, k0, k1, v0, v1, feats0, feats1, edges,
      Wskv0, Wskv1, Wbias, sbias, nbias, nk0, nk1, nv0, nv1, hw1,
      Wout0, Wout1, nmask, (float*)d_out, n);
}